// Round 3
// baseline (193.661 us; speedup 1.0000x reference)
//
#include <hip/hip_runtime.h>
#include <stdint.h>

#define B_ROWS 4096
#define D_IN   2048
#define D_OUT  2048
#define KANCH  4

typedef _Float16 half8  __attribute__((ext_vector_type(8)));
typedef _Float16 half4  __attribute__((ext_vector_type(4)));
typedef float    floatx4 __attribute__((ext_vector_type(4)));
typedef const __attribute__((address_space(1))) uint8_t* gptr_t;
typedef __attribute__((address_space(3))) uint8_t* lptr_t;

// K0w: convert W (f32) -> Wh (fp16)
__global__ __launch_bounds__(256) void k_convw(
    const float* __restrict__ W, _Float16* __restrict__ Wh)
{
    int idx = blockIdx.x * 256 + threadIdx.x;   // one float4 per thread
    const floatx4* W4 = (const floatx4*)W;
    floatx4 v = W4[idx];
    half4 h = {(_Float16)v[0], (_Float16)v[1], (_Float16)v[2], (_Float16)v[3]};
    *(half4*)(Wh + (size_t)idx * 4) = h;
}

// K0x: per-row (1 wave per row): xh = fp16(x); n2x[b]=||x_b||^2; sprow[b]=softplus(x_b.cw+cb)
__global__ __launch_bounds__(256) void k_convx_rowstats(
    const float* __restrict__ x,
    const float* __restrict__ cw,
    const float* __restrict__ cb,
    _Float16* __restrict__ xh,
    float* __restrict__ n2x, float* __restrict__ sprow)
{
    int w = threadIdx.x >> 6, lane = threadIdx.x & 63;
    int row = blockIdx.x * 4 + w;
    const floatx4* xr = (const floatx4*)(x + (size_t)row * D_IN);
    const floatx4* wr = (const floatx4*)cw;
    _Float16* xo = xh + (size_t)row * D_IN;
    float dot = 0.f, ss = 0.f;
#pragma unroll
    for (int i = 0; i < 8; ++i) {
        int idx = i * 64 + lane;
        floatx4 xv = xr[idx];
        floatx4 wv = wr[idx];
#pragma unroll
        for (int j = 0; j < 4; ++j) {
            dot += xv[j] * wv[j];
            ss  += xv[j] * xv[j];
        }
        half4 h = {(_Float16)xv[0], (_Float16)xv[1], (_Float16)xv[2], (_Float16)xv[3]};
        *(half4*)(xo + idx * 4) = h;
    }
#pragma unroll
    for (int off = 32; off; off >>= 1) {
        dot += __shfl_down(dot, off);
        ss  += __shfl_down(ss, off);
    }
    if (lane == 0) {
        n2x[row] = ss;
        float z = dot + cb[0];
        sprow[row] = (z > 20.f) ? z : log1pf(expf(z));
    }
}

// K2: scal[1]=c (mean softplus); scal[2..5]=||a_k||^2; frow[b]=artanh(clip(sc*n))/(sc*n)
__global__ __launch_bounds__(256) void k_finalize(
    const float* __restrict__ anchors,
    const float* __restrict__ n2x,
    const float* __restrict__ sprow,
    float* __restrict__ frow,
    float* __restrict__ scal)
{
    int tid = threadIdx.x, w = tid >> 6, lane = tid & 63;
    __shared__ float spw[4];
    __shared__ float s_c;
    // phase A: reduce sprow -> c
    float sp = 0.f;
#pragma unroll
    for (int i = 0; i < 16; ++i) sp += sprow[tid + 256 * i];
#pragma unroll
    for (int off = 32; off; off >>= 1) sp += __shfl_down(sp, off);
    if (lane == 0) spw[w] = sp;
    // phase B: anchor squared norms (one wave per anchor)
    const floatx4* ar = (const floatx4*)(anchors + (size_t)w * D_OUT);
    float aa = 0.f;
#pragma unroll
    for (int i = 0; i < 8; ++i) {
        floatx4 av = ar[i * 64 + lane];
#pragma unroll
        for (int j = 0; j < 4; ++j) aa += av[j] * av[j];
    }
#pragma unroll
    for (int off = 32; off; off >>= 1) aa += __shfl_down(aa, off);
    if (lane == 0) scal[2 + w] = aa;
    __syncthreads();
    if (tid == 0) {
        float c = (spw[0] + spw[1] + spw[2] + spw[3]) * (1.0f / (float)B_ROWS);
        scal[1] = c;   // BASE_CURVATURE = 1
        s_c = c;
    }
    __syncthreads();
    float sc = sqrtf(s_c);
    for (int b = tid; b < B_ROWS; b += 256) {
        float n = fmaxf(sqrtf(n2x[b]), 1e-6f);
        float a = sc * n;
        float zc = fminf(fmaxf(a, -1.0f + 1e-5f), 1.0f - 1e-5f);
        frow[b] = atanhf(zc) / a;
    }
}

// K3: H[b,j] = frow[b] * (x @ W^T)[b,j] + bias[j]  (f32 out to d_out)
// m97-style: 128x128 tile, BK=64, global_load_lds w=16, 4 waves of 4x4 16x16x32 f16 MFMA
__global__ __launch_bounds__(256) void k_gemm(
    const _Float16* __restrict__ A,
    const _Float16* __restrict__ W,
    const float* __restrict__ bias,
    const float* __restrict__ frow,
    float* __restrict__ H)
{
    constexpr int K = D_IN;
    __shared__ __align__(16) _Float16 As[128 * 64];
    __shared__ __align__(16) _Float16 Bs[128 * 64];
    int tid = threadIdx.x;
    int lane = tid & 63;
    int w = tid >> 6;
    int wm = (w >> 1) * 64, wn = (w & 1) * 64;
    int bm0 = blockIdx.y * 128, bn0 = blockIdx.x * 128;

    floatx4 acc[4][4];
#pragma unroll
    for (int mi = 0; mi < 4; ++mi)
#pragma unroll
        for (int ni = 0; ni < 4; ++ni)
            acc[mi][ni] = (floatx4){0.f, 0.f, 0.f, 0.f};

    for (int k0 = 0; k0 < K; k0 += 64) {
#pragma unroll
        for (int i = 0; i < 4; ++i) {
            int e = (i * 256 + tid) * 8;     // element index within 128x64 tile
            int r = e >> 6, kk = e & 63;
            __builtin_amdgcn_global_load_lds(
                (gptr_t)(A + (size_t)(bm0 + r) * K + k0 + kk),
                (lptr_t)(As + e), 16, 0, 0);
            __builtin_amdgcn_global_load_lds(
                (gptr_t)(W + (size_t)(bn0 + r) * K + k0 + kk),
                (lptr_t)(Bs + e), 16, 0, 0);
        }
        __syncthreads();
#pragma unroll
        for (int ks = 0; ks < 64; ks += 32) {
            int kq = ks + (lane >> 4) * 8;
            half8 afr[4], bfr[4];
#pragma unroll
            for (int mi = 0; mi < 4; ++mi)
                afr[mi] = *(const half8*)(As + (wm + mi * 16 + (lane & 15)) * 64 + kq);
#pragma unroll
            for (int ni = 0; ni < 4; ++ni)
                bfr[ni] = *(const half8*)(Bs + (wn + ni * 16 + (lane & 15)) * 64 + kq);
#pragma unroll
            for (int mi = 0; mi < 4; ++mi)
#pragma unroll
                for (int ni = 0; ni < 4; ++ni)
                    acc[mi][ni] = __builtin_amdgcn_mfma_f32_16x16x32_f16(
                        afr[mi], bfr[ni], acc[mi][ni], 0, 0, 0);
        }
        __syncthreads();
    }
    // epilogue: C/D layout col=lane&15, row=(lane>>4)*4+r
#pragma unroll
    for (int mi = 0; mi < 4; ++mi) {
#pragma unroll
        for (int r = 0; r < 4; ++r) {
            int gm = bm0 + wm + mi * 16 + (lane >> 4) * 4 + r;
            float f = frow[gm];
#pragma unroll
            for (int ni = 0; ni < 4; ++ni) {
                int gn = bn0 + wn + ni * 16 + (lane & 15);
                H[(size_t)gm * D_OUT + gn] = f * acc[mi][ni][r] + bias[gn];
            }
        }
    }
}

// K4: per row: reduce ||h||^2, dot(h,a_k) -> closed-form Mobius coefficients ->
//     out[b,:] = Ch*h[b,:] + sum_k Ca_k*a_k[:]   (in place on d_out, f32)
__global__ __launch_bounds__(256) void k_mobius(
    const float* __restrict__ anchors,
    const float* __restrict__ tv,
    const float* __restrict__ aw,
    const float* __restrict__ scal,
    float* __restrict__ out)
{
    int tid = threadIdx.x, w = tid >> 6, lane = tid & 63;
    size_t rowoff = (size_t)blockIdx.x * D_OUT;
    float hf[8];
    *(floatx4*)(hf)     = *(const floatx4*)(out + rowoff + tid * 8);
    *(floatx4*)(hf + 4) = *(const floatx4*)(out + rowoff + tid * 8 + 4);
    float af[KANCH][8];
#pragma unroll
    for (int k = 0; k < KANCH; ++k) {
        *(floatx4*)(af[k])     = *(const floatx4*)(anchors + (size_t)k * D_OUT + tid * 8);
        *(floatx4*)(af[k] + 4) = *(const floatx4*)(anchors + (size_t)k * D_OUT + tid * 8 + 4);
    }
    float v[5] = {0.f, 0.f, 0.f, 0.f, 0.f};
#pragma unroll
    for (int j = 0; j < 8; ++j) {
        v[0] += hf[j] * hf[j];
#pragma unroll
        for (int k = 0; k < KANCH; ++k) v[1 + k] += hf[j] * af[k][j];
    }
#pragma unroll
    for (int off = 32; off; off >>= 1)
#pragma unroll
        for (int q = 0; q < 5; ++q) v[q] += __shfl_down(v[q], off);
    __shared__ float red[4][5];
    if (lane == 0)
#pragma unroll
        for (int q = 0; q < 5; ++q) red[w][q] = v[q];
    __syncthreads();
    __shared__ float coef[1 + KANCH];
    if (tid == 0) {
        float hh = red[0][0] + red[1][0] + red[2][0] + red[3][0];
        float ha[KANCH];
        for (int k = 0; k < KANCH; ++k)
            ha[k] = red[0][1 + k] + red[1][1 + k] + red[2][1 + k] + red[3][1 + k];
        float c = scal[1], sc = sqrtf(c);
        // softmax(anchor_weights)
        float mx = -1e30f;
        for (int k = 0; k < KANCH; ++k) mx = fmaxf(mx, aw[k]);
        float se = 0.f, wk[KANCH];
        for (int k = 0; k < KANCH; ++k) { wk[k] = expf(aw[k] - mx); se += wk[k]; }
        for (int k = 0; k < KANCH; ++k) wk[k] /= se;
        // y = expmap0(h): y = gy*h
        float nh = fmaxf(sqrtf(hh), 1e-6f);
        float snh = sc * nh;
        float gy = tanhf(snh) / snh;
        float x2 = gy * gy * hh;           // ||y||^2
        float B1 = 1.f - c * x2;           // shared by both mobius_adds
        float ch = 0.f;
        for (int k = 0; k < KANCH; ++k) {
            float y2 = scal[2 + k];        // ||a_k||^2
            float dy = gy * ha[k];         // dot(y, a_k)
            float xy1 = -dy;               // mobius_add(-y, a)
            float A1 = 1.f + 2.f * c * xy1 + c * y2;
            float den1 = fmaxf(1.f + 2.f * c * xy1 + c * c * x2 * y2, 1e-6f);
            float al = -A1 / den1, be = B1 / den1;   // diff = al*y + be*a
            float nd2 = fmaxf(al * al * x2 + 2.f * al * be * dy + be * be * y2, 0.f);
            float nd = fmaxf(sqrtf(nd2), 1e-6f);
            float snd = sc * nd;
            float zc = fminf(fmaxf(snd, -1.f + 1e-5f), 1.f - 1e-5f);
            float s = tanhf(tv[k] * atanhf(zc)) / snd;  // step = s*diff
            float y2s = s * s * nd2;                 // ||step||^2
            float xys = s * (al * x2 + be * dy);     // dot(y, step)
            float A2 = 1.f + 2.f * c * xys + c * y2s;
            float den2 = fmaxf(1.f + 2.f * c * xys + c * c * x2 * y2s, 1e-6f);
            float Cy  = (A2 + B1 * s * al) / den2;   // g = Cy*y + Cak*a
            float Cak = (B1 * s * be) / den2;
            ch += wk[k] * Cy;
            coef[1 + k] = wk[k] * Cak;
        }
        coef[0] = gy * ch;   // multiplies h directly
    }
    __syncthreads();
    float Ch = coef[0];
    float o[8];
#pragma unroll
    for (int j = 0; j < 8; ++j) {
        float val = Ch * hf[j];
#pragma unroll
        for (int k = 0; k < KANCH; ++k) val += coef[1 + k] * af[k][j];
        o[j] = val;
    }
    *(floatx4*)(out + rowoff + tid * 8)     = *(floatx4*)(o);
    *(floatx4*)(out + rowoff + tid * 8 + 4) = *(floatx4*)(o + 4);
}

extern "C" void kernel_launch(void* const* d_in, const int* in_sizes, int n_in,
                              void* d_out, int out_size, void* d_ws, size_t ws_size,
                              hipStream_t stream) {
    const float* x       = (const float*)d_in[0];
    const float* wt      = (const float*)d_in[1];
    const float* bias    = (const float*)d_in[2];
    const float* cw      = (const float*)d_in[3];
    const float* cb      = (const float*)d_in[4];
    const float* anchors = (const float*)d_in[5];
    const float* tv      = (const float*)d_in[6];
    const float* aw      = (const float*)d_in[7];
    float* out = (float*)d_out;

    // ws layout: Wh fp16 (8.39 MB) | xh fp16 (16.78 MB) | n2x | sprow | frow | scal  (~25.2 MB)
    _Float16* Wh = (_Float16*)d_ws;
    _Float16* xh = Wh + (size_t)D_OUT * D_IN;
    float* fws   = (float*)(xh + (size_t)B_ROWS * D_IN);
    float* n2x   = fws;
    float* sprow = n2x + B_ROWS;
    float* frow  = sprow + B_ROWS;
    float* scal  = frow + B_ROWS;

    k_convw<<<(D_OUT * D_IN) / (256 * 4), 256, 0, stream>>>(wt, Wh);
    k_convx_rowstats<<<B_ROWS / 4, 256, 0, stream>>>(x, cw, cb, xh, n2x, sprow);
    k_finalize<<<1, 256, 0, stream>>>(anchors, n2x, sprow, frow, scal);
    // h lives in d_out (f32); K4 rewrites d_out in place (block b touches only row b)
    k_gemm<<<dim3(D_OUT / 128, B_ROWS / 128), 256, 0, stream>>>(xh, Wh, bias, frow, out);
    k_mobius<<<B_ROWS, 256, 0, stream>>>(anchors, tv, aw, scal, out);
}